// Round 10
// baseline (150.033 us; speedup 1.0000x reference)
//
#include <hip/hip_runtime.h>
#include <hip/hip_fp16.h>

#define NP    128   // planets per batch
#define NH    64    // hidden dim
#define LDH   72    // slab row stride in f16 elems (16B-aligned rows, 2-way-max banks)
#define ITERS 4     // batches per wave
#define WPB   4     // waves per block

typedef __attribute__((ext_vector_type(8))) _Float16 f16x8;   // MFMA A/B operand, K=32
typedef __attribute__((ext_vector_type(4))) _Float16 f16x4;   // MFMA A/B operand, K=16
typedef __attribute__((ext_vector_type(2))) __fp16  hf16x2;   // return type of cvt_pkrtz
typedef __attribute__((ext_vector_type(4))) float f32x4;
typedef __attribute__((ext_vector_type(2))) float f32x2;

union FragK32 { f16x8 v; unsigned int u[4]; };
union FragK16 { f16x4 v; unsigned int u[2]; };

__device__ __forceinline__ unsigned int pack_pkrtz(float a, float b) {
    hf16x2 t = __builtin_amdgcn_cvt_pkrtz(a, b);
    return __builtin_bit_cast(unsigned int, t);
}

// packed f16 relu: v_pk_max_f16 with +0. relu(rtz(x)) == rtz(relu(x)).
__device__ __forceinline__ unsigned int relu2_pk(unsigned int u) {
    hf16x2 h = __builtin_bit_cast(hf16x2, u);
    h = __builtin_elementwise_max(h, (hf16x2)(__fp16)0.f);
    return __builtin_bit_cast(unsigned int, h);
}

// 256-thread blocks = 4 independent waves; each wave owns ITERS consecutive
// batches and a private LDS slab double-buffer. No __syncthreads, no manual
// waitcnt: all slab traffic is within-wave, and a wave's DS ops execute in
// order, so a later ds_read observes an earlier ds_write without a drain.
// launch_bounds (256, 2): VGPR cap 256 — kernel needs ~110-130 arch VGPRs;
// tighter caps (R6: 84, R7: 64) caused 78-404 MB of scratch spill traffic.
__global__ void __launch_bounds__(256, 2) gnn_wave(
    const float* __restrict__ planet_xy,  // [B][P][2]
    const float* __restrict__ planet_m,   // [P]
    const float* __restrict__ ast_xy,     // [B][2]
    const float* __restrict__ W1,         // [4][64]
    const float* __restrict__ b1,         // [64]
    const float* __restrict__ W2,         // [64][64]
    const float* __restrict__ b2,         // [64]
    float* __restrict__ out)              // [B][64]
{
    __shared__ alignas(16) unsigned short slab[WPB][2][16 * LDH];

    const int tid  = threadIdx.x;
    const int wv   = tid >> 6;
    const int lane = tid & 63;
    const int q    = lane >> 4;
    const int lm   = lane & 15;
    const bool q0  = (q == 0);
    const bool q1  = (q == 1);

    // ---- layer1 weight fragments (16x16x16f16), b1 FOLDED as feature k=4 ----
    // A[m=16mt+lm][k=4q+j]: k<4 -> W1[k][m]; k==4 (q==1,j==0) -> b1[m]; else 0.
    FragK16 w1f[4];
    #pragma unroll
    for (int mt = 0; mt < 4; mt++) {
        const int m = 16 * mt + lm;
        float wa = W1[0 * NH + m], wb = W1[1 * NH + m];
        float wc = W1[2 * NH + m], wd = W1[3 * NH + m];
        float be = b1[m];
        w1f[mt].u[0] = q0 ? pack_pkrtz(wa, wb) : (q1 ? pack_pkrtz(be, 0.f) : 0u);
        w1f[mt].u[1] = q0 ? pack_pkrtz(wc, wd) : 0u;
    }

    // ---- layer2 weight fragments (16x16x32): B[k=32kk+8q+j][n=16np+lm] ----
    FragK32 w2f[2][4];
    #pragma unroll
    for (int kk = 0; kk < 2; kk++)
        #pragma unroll
        for (int np = 0; np < 4; np++)
            #pragma unroll
            for (int jp = 0; jp < 4; jp++) {
                float r0 = W2[(32 * kk + 8 * q + 2 * jp + 0) * NH + 16 * np + lm];
                float r1 = W2[(32 * kk + 8 * q + 2 * jp + 1) * NH + 16 * np + lm];
                w2f[kk][np].u[jp] = pack_pkrtz(r0, r1);
            }

    // b2 as layer2 C-init (col = 16np+lm, same for all 4 row-regs)
    f32x4 b2f[4];
    #pragma unroll
    for (int np = 0; np < 4; np++) {
        float v = b2[16 * np + lm];
        b2f[np] = (f32x4){v, v, v, v};
    }

    // batch-invariant planet masses (planet 16*i + lm)
    float pmv[8];
    #pragma unroll
    for (int i = 0; i < 8; i++)
        pmv[i] = planet_m[16 * i + lm];

    // batch-invariant parts of the layer1 B-fragment for q!=0 lanes:
    // q1 carries the constant-1 "bias feature" at k=4.
    const unsigned int bf0_const = q1 ? pack_pkrtz(1.f, 0.f) : 0u;

    const f32x4 zf = (f32x4){0.f, 0.f, 0.f, 0.f};
    int b = (blockIdx.x * WPB + wv) * ITERS;

    for (int it = 0; it < ITERS; ++it, ++b) {
        const float2 axy = *(const float2*)&ast_xy[2 * b];
        float2 pxy[8];
        #pragma unroll
        for (int i = 0; i < 8; i++)
            pxy[i] = *(const float2*)&planet_xy[((size_t)b * NP + 16 * i + lm) * 2];

        f32x2 sum2[4];
        #pragma unroll
        for (int np = 0; np < 4; np++)
            sum2[np] = (f32x2){0.f, 0.f};

        // ---- slab 0: layer1 for planets 0..15 ----
        {
            float dx = pxy[0].x - axy.x, dy = pxy[0].y - axy.y;
            float inv = __builtin_amdgcn_rsqf(fmaf(dx, dx, fmaf(dy, dy, 1e-6f)));
            FragK16 bf;
            bf.u[0] = q0 ? pack_pkrtz(dx, dy)      : bf0_const;
            bf.u[1] = q0 ? pack_pkrtz(inv, pmv[0]) : 0u;
            #pragma unroll
            for (int mt = 0; mt < 4; mt++) {
                f32x4 c = __builtin_amdgcn_mfma_f32_16x16x16f16(w1f[mt].v, bf.v, zf, 0, 0, 0);
                unsigned int d0 = relu2_pk(pack_pkrtz(c[0], c[1]));
                unsigned int d1 = relu2_pk(pack_pkrtz(c[2], c[3]));
                *(uint2*)&slab[wv][0][lm * LDH + 4 * q + 16 * mt] = make_uint2(d0, d1);
            }
        }

        #pragma unroll
        for (int mi = 0; mi < 8; ++mi) {
            const int buf = mi & 1;
            // same-wave DS ops execute in order: these reads see the writes above
            f16x8 a0 = *(const f16x8*)&slab[wv][buf][lm * LDH + 0  + 8 * q];
            f16x8 a1 = *(const f16x8*)&slab[wv][buf][lm * LDH + 32 + 8 * q];

            // produce next slab while the reads are in flight
            if (mi < 7) {
                float dx = pxy[mi + 1].x - axy.x, dy = pxy[mi + 1].y - axy.y;
                float inv = __builtin_amdgcn_rsqf(fmaf(dx, dx, fmaf(dy, dy, 1e-6f)));
                FragK16 bf;
                bf.u[0] = q0 ? pack_pkrtz(dx, dy)           : bf0_const;
                bf.u[1] = q0 ? pack_pkrtz(inv, pmv[mi + 1]) : 0u;
                #pragma unroll
                for (int mt = 0; mt < 4; mt++) {
                    f32x4 c = __builtin_amdgcn_mfma_f32_16x16x16f16(w1f[mt].v, bf.v, zf, 0, 0, 0);
                    unsigned int d0 = relu2_pk(pack_pkrtz(c[0], c[1]));
                    unsigned int d1 = relu2_pk(pack_pkrtz(c[2], c[3]));
                    *(uint2*)&slab[wv][buf ^ 1][lm * LDH + 4 * q + 16 * mt] = make_uint2(d0, d1);
                }
            }

            // layer2: 16-planet x 64-col tile, bias via C-operand
            #pragma unroll
            for (int np = 0; np < 4; np++) {
                f32x4 acc = __builtin_amdgcn_mfma_f32_16x16x32_f16(a0, w2f[0][np].v, b2f[np], 0, 0, 0);
                acc = __builtin_amdgcn_mfma_f32_16x16x32_f16(a1, w2f[1][np].v, acc, 0, 0, 0);
                float m0 = fmaxf(acc[0], 0.f), m1 = fmaxf(acc[1], 0.f);
                float m2 = fmaxf(acc[2], 0.f), m3 = fmaxf(acc[3], 0.f);
                sum2[np] += (f32x2){m0, m1};       // v_pk_add_f32
                sum2[np] += (f32x2){m2, m3};
            }
        }

        // ---- cross-quad reduction + store ----
        #pragma unroll
        for (int np = 0; np < 4; np++) {
            float s = sum2[np].x + sum2[np].y;
            s += __shfl_xor(s, 16, 64);
            s += __shfl_xor(s, 32, 64);
            if (q0) out[(size_t)b * NH + 16 * np + lm] = s;
        }
    }
}

extern "C" void kernel_launch(void* const* d_in, const int* in_sizes, int n_in,
                              void* d_out, int out_size, void* d_ws, size_t ws_size,
                              hipStream_t stream) {
    const float* planet_xy = (const float*)d_in[0];
    const float* planet_m  = (const float*)d_in[1];
    const float* ast_xy    = (const float*)d_in[2];
    const float* W1        = (const float*)d_in[3];
    const float* b1        = (const float*)d_in[4];
    const float* W2        = (const float*)d_in[5];
    const float* b2        = (const float*)d_in[6];
    float* outp            = (float*)d_out;

    const int B = in_sizes[2] / 2;   // ast_xy is [B][2]
    const int batches_per_block = WPB * ITERS;
    const int grid = (B + batches_per_block - 1) / batches_per_block;

    gnn_wave<<<grid, 256, 0, stream>>>(planet_xy, planet_m, ast_xy, W1, b1, W2, b2, outp);
}

// Round 11
// 139.714 us; speedup vs baseline: 1.0739x; 1.0739x over previous
//
#include <hip/hip_runtime.h>
#include <hip/hip_fp16.h>

#define NP    128   // planets per batch
#define NH    64    // hidden dim
#define RST   18    // epilogue LDS row stride in floats (even -> b64-aligned reads)
#define ITERS 4     // batches per wave
#define WPB   4     // waves per block

typedef __attribute__((ext_vector_type(4))) _Float16 f16x4;   // K16 MFMA A/B operand
typedef __attribute__((ext_vector_type(2))) __fp16  hf16x2;   // cvt_pkrtz return type
typedef __attribute__((ext_vector_type(4))) float f32x4;

union FragK16 { f16x4 v; unsigned int u[2]; };

__device__ __forceinline__ unsigned int pack_pkrtz(float a, float b) {
    hf16x2 t = __builtin_amdgcn_cvt_pkrtz(a, b);
    return __builtin_bit_cast(unsigned int, t);
}

// packed f16 relu (v_pk_max_f16). relu(rtz(x)) == rtz(relu(x)).
__device__ __forceinline__ unsigned int relu2_pk(unsigned int u) {
    hf16x2 h = __builtin_bit_cast(hf16x2, u);
    h = __builtin_elementwise_max(h, (hf16x2)(__fp16)0.f);
    return __builtin_bit_cast(unsigned int, h);
}

// 4 independent waves per block, each owning ITERS batches. The entire
// per-slab pipeline lives in registers: layer1 K16-MFMA C-output (rows 4q+r,
// col lm), packed to f16, IS the B-operand layout (k=4q+j, col lm) for the
// layer2 K16 MFMAs (msgT = W2T x hT). LDS is used only once per batch for the
// 16-lane planet-sum transpose. No __syncthreads / waitcnt: all LDS traffic is
// same-wave, and a wave's DS ops execute in order (validated R10: absmax held).
// launch_bounds (256,2): VGPR cap 256 — needs ~140 arch VGPRs; tighter caps
// (R6: 84, R7: 64) caused 78-404 MB scratch-spill traffic.
__global__ void __launch_bounds__(256, 2) gnn_wave(
    const float* __restrict__ planet_xy,  // [B][P][2]
    const float* __restrict__ planet_m,   // [P]
    const float* __restrict__ ast_xy,     // [B][2]
    const float* __restrict__ W1,         // [4][64]
    const float* __restrict__ b1,         // [64]
    const float* __restrict__ W2,         // [64][64]
    const float* __restrict__ b2,         // [64]
    float* __restrict__ out)              // [B][64]
{
    __shared__ float rsum[WPB][64 * RST];

    const int tid  = threadIdx.x;
    const int wv   = tid >> 6;
    const int lane = tid & 63;
    const int q    = lane >> 4;
    const int lm   = lane & 15;
    const bool q0  = (q == 0);
    const bool q1  = (q == 1);

    // ---- layer1 A-frags (16x16x16), b1 folded as constant-1 feature k=4 ----
    // A[m=16mt+lm][k=4q+j]: k<4 -> W1[k][m]; k==4 -> b1[m]; else 0.
    FragK16 w1f[4];
    #pragma unroll
    for (int mt = 0; mt < 4; mt++) {
        const int m = 16 * mt + lm;
        float wa = W1[0 * NH + m], wb = W1[1 * NH + m];
        float wc = W1[2 * NH + m], wd = W1[3 * NH + m];
        float be = b1[m];
        w1f[mt].u[0] = q0 ? pack_pkrtz(wa, wb) : (q1 ? pack_pkrtz(be, 0.f) : 0u);
        w1f[mt].u[1] = q0 ? pack_pkrtz(wc, wd) : 0u;
    }

    // ---- layer2 A-frags: A[m=n'][k=16mt+4q+j] = W2[16mt+4q+j][16np+n'] ----
    FragK16 w2tf[4][4];   // [np][mt]
    #pragma unroll
    for (int np = 0; np < 4; np++)
        #pragma unroll
        for (int mt = 0; mt < 4; mt++) {
            const int kbase = 16 * mt + 4 * q;
            const int n = 16 * np + lm;
            float r0 = W2[(kbase + 0) * NH + n];
            float r1 = W2[(kbase + 1) * NH + n];
            float r2 = W2[(kbase + 2) * NH + n];
            float r3 = W2[(kbase + 3) * NH + n];
            w2tf[np][mt].u[0] = pack_pkrtz(r0, r1);
            w2tf[np][mt].u[1] = pack_pkrtz(r2, r3);
        }

    // b2 as layer2 C-init: rows n = 16np+4q+r (contiguous b128 load)
    f32x4 b2f[4];
    #pragma unroll
    for (int np = 0; np < 4; np++)
        b2f[np] = *(const f32x4*)&b2[16 * np + 4 * q];

    // batch-invariant planet masses (planet 16*i + lm)
    float pmv[8];
    #pragma unroll
    for (int i = 0; i < 8; i++)
        pmv[i] = planet_m[16 * i + lm];

    const unsigned int bf0_const = q1 ? pack_pkrtz(1.f, 0.f) : 0u;
    const f32x4 zf = (f32x4){0.f, 0.f, 0.f, 0.f};

    int b = (blockIdx.x * WPB + wv) * ITERS;

    for (int it = 0; it < ITERS; ++it, ++b) {
        const float2 axy = *(const float2*)&ast_xy[2 * b];
        float2 pxy[8];
        #pragma unroll
        for (int i = 0; i < 8; i++)
            pxy[i] = *(const float2*)&planet_xy[((size_t)b * NP + 16 * i + lm) * 2];

        f32x4 sums[4];
        #pragma unroll
        for (int np = 0; np < 4; np++)
            sums[np] = zf;

        #pragma unroll
        for (int mi = 0; mi < 8; ++mi) {
            // feats B-frag for planets 16mi..16mi+15
            float dx = pxy[mi].x - axy.x, dy = pxy[mi].y - axy.y;
            float inv = __builtin_amdgcn_rsqf(fmaf(dx, dx, fmaf(dy, dy, 1e-6f)));
            FragK16 bf;
            bf.u[0] = q0 ? pack_pkrtz(dx, dy)        : bf0_const;
            bf.u[1] = q0 ? pack_pkrtz(inv, pmv[mi])  : 0u;

            // layer1: hT fragments straight into registers (C layout -> B layout)
            FragK16 hb[4];
            #pragma unroll
            for (int mt = 0; mt < 4; mt++) {
                f32x4 c = __builtin_amdgcn_mfma_f32_16x16x16f16(w1f[mt].v, bf.v, zf, 0, 0, 0);
                hb[mt].u[0] = relu2_pk(pack_pkrtz(c[0], c[1]));
                hb[mt].u[1] = relu2_pk(pack_pkrtz(c[2], c[3]));
            }

            // layer2: msgT tile (rows n=16np+4q+r, col p=lm), bias via C-init
            #pragma unroll
            for (int np = 0; np < 4; np++) {
                f32x4 acc = b2f[np];
                #pragma unroll
                for (int mt = 0; mt < 4; mt++)
                    acc = __builtin_amdgcn_mfma_f32_16x16x16f16(w2tf[np][mt].v, hb[mt].v, acc, 0, 0, 0);
                sums[np] += __builtin_elementwise_max(acc, zf);   // relu + accumulate
            }
        }

        // ---- per-batch transpose-reduce over the 16 lm lanes via LDS ----
        #pragma unroll
        for (int np = 0; np < 4; np++)
            #pragma unroll
            for (int r = 0; r < 4; r++)
                rsum[wv][(16 * np + 4 * q + r) * RST + lm] = sums[np][r];

        // same-wave in-order DS: reads below observe the writes above
        float tot = 0.f;
        #pragma unroll
        for (int i = 0; i < 8; i++) {
            float2 v = *(const float2*)&rsum[wv][lane * RST + 2 * i];
            tot += v.x + v.y;
        }
        out[(size_t)b * NH + lane] = tot;
    }
}

extern "C" void kernel_launch(void* const* d_in, const int* in_sizes, int n_in,
                              void* d_out, int out_size, void* d_ws, size_t ws_size,
                              hipStream_t stream) {
    const float* planet_xy = (const float*)d_in[0];
    const float* planet_m  = (const float*)d_in[1];
    const float* ast_xy    = (const float*)d_in[2];
    const float* W1        = (const float*)d_in[3];
    const float* b1        = (const float*)d_in[4];
    const float* W2        = (const float*)d_in[5];
    const float* b2        = (const float*)d_in[6];
    float* outp            = (float*)d_out;

    const int B = in_sizes[2] / 2;   // ast_xy is [B][2]
    const int batches_per_block = WPB * ITERS;
    const int grid = (B + batches_per_block - 1) / batches_per_block;

    gnn_wave<<<grid, 256, 0, stream>>>(planet_xy, planet_m, ast_xy, W1, b1, W2, b2, outp);
}

// Round 12
// 129.663 us; speedup vs baseline: 1.1571x; 1.0775x over previous
//
#include <hip/hip_runtime.h>
#include <hip/hip_fp16.h>

#define NP    128   // planets per batch
#define NH    64    // hidden dim
#define RST   18    // epilogue LDS row stride in floats (even -> b64-aligned reads)
#define ITERS 4     // batches per wave
#define WPB   4     // waves per block

typedef __attribute__((ext_vector_type(8))) _Float16 f16x8;   // K32 MFMA A/B operand
typedef __attribute__((ext_vector_type(4))) _Float16 f16x4;   // K16 MFMA A/B operand
typedef __attribute__((ext_vector_type(2))) __fp16  hf16x2;   // cvt_pkrtz return type
typedef __attribute__((ext_vector_type(4))) float f32x4;

union FragK16 { f16x4 v; unsigned int u[2]; };
union FragK32 { f16x8 v; unsigned int u[4]; };

__device__ __forceinline__ unsigned int pack_pkrtz(float a, float b) {
    hf16x2 t = __builtin_amdgcn_cvt_pkrtz(a, b);
    return __builtin_bit_cast(unsigned int, t);
}

// packed f16 relu (v_pk_max_f16). relu(rtz(x)) == rtz(relu(x)).
__device__ __forceinline__ unsigned int relu2_pk(unsigned int u) {
    hf16x2 h = __builtin_bit_cast(hf16x2, u);
    h = __builtin_elementwise_max(h, (hf16x2)(__fp16)0.f);
    return __builtin_bit_cast(unsigned int, h);
}

// 4 independent waves/block, ITERS batches each, fully register-resident.
// h-PERMUTATION TRICK: the h dimension is internal, so we pick the permutation
// sigma(32kk+8q+j) = 16*(2kk+(j>>2)) + 4q + (j&3), which makes the K32 layer2
// B-operand EXACTLY the concatenation of two layer1 K16 C-output fragments —
// no cross-lane movement. W2 is loaded with sigma-permuted rows at setup.
// Layer2 thus runs on full-rate 16x16x32 MFMA (64/batch) instead of half-rate
// K16 (128/batch). LDS only for the per-batch 16-lane transpose-reduce;
// same-wave DS ops are in-order (validated R10/R11), so no barriers at all.
// launch_bounds (256,2): VGPR cap 256 — tighter caps (R6/R7) caused massive
// scratch spills.
__global__ void __launch_bounds__(256, 2) gnn_wave(
    const float* __restrict__ planet_xy,  // [B][P][2]
    const float* __restrict__ planet_m,   // [P]
    const float* __restrict__ ast_xy,     // [B][2]
    const float* __restrict__ W1,         // [4][64]
    const float* __restrict__ b1,         // [64]
    const float* __restrict__ W2,         // [64][64]
    const float* __restrict__ b2,         // [64]
    float* __restrict__ out)              // [B][64]
{
    __shared__ float rsum[WPB][64 * RST];

    const int tid  = threadIdx.x;
    const int wv   = tid >> 6;
    const int lane = tid & 63;
    const int q    = lane >> 4;
    const int lm   = lane & 15;
    const bool q0  = (q == 0);
    const bool q1  = (q == 1);

    // ---- layer1 A-frags (16x16x16), b1 folded as constant-1 feature k=4 ----
    // A[m=16mt+lm][k=4q+j]: k<4 -> W1[k][m]; k==4 -> b1[m]; else 0.
    FragK16 w1f[4];
    #pragma unroll
    for (int mt = 0; mt < 4; mt++) {
        const int m = 16 * mt + lm;
        float wa = W1[0 * NH + m], wb = W1[1 * NH + m];
        float wc = W1[2 * NH + m], wd = W1[3 * NH + m];
        float be = b1[m];
        w1f[mt].u[0] = q0 ? pack_pkrtz(wa, wb) : (q1 ? pack_pkrtz(be, 0.f) : 0u);
        w1f[mt].u[1] = q0 ? pack_pkrtz(wc, wd) : 0u;
    }

    // ---- layer2 A-frags (16x16x32), sigma-permuted W2^T ----
    // A[m'][k=32kk+8q+j] = W2[sigma(k)][16np+lm],
    // sigma(32kk+8q+j) = 16*(2kk+(j>>2)) + 4q + (j&3).
    FragK32 w2a[4][2];   // [np][kk]
    #pragma unroll
    for (int np = 0; np < 4; np++)
        #pragma unroll
        for (int kk = 0; kk < 2; kk++) {
            const int n = 16 * np + lm;
            const int k0 = 32 * kk + 4 * q;        // j>>2 == 0 rows
            const int k1 = 32 * kk + 16 + 4 * q;   // j>>2 == 1 rows
            w2a[np][kk].u[0] = pack_pkrtz(W2[(k0 + 0) * NH + n], W2[(k0 + 1) * NH + n]);
            w2a[np][kk].u[1] = pack_pkrtz(W2[(k0 + 2) * NH + n], W2[(k0 + 3) * NH + n]);
            w2a[np][kk].u[2] = pack_pkrtz(W2[(k1 + 0) * NH + n], W2[(k1 + 1) * NH + n]);
            w2a[np][kk].u[3] = pack_pkrtz(W2[(k1 + 2) * NH + n], W2[(k1 + 3) * NH + n]);
        }

    // b2 as layer2 C-init: rows n = 16np+4q+r (contiguous b128 load)
    f32x4 b2f[4];
    #pragma unroll
    for (int np = 0; np < 4; np++)
        b2f[np] = *(const f32x4*)&b2[16 * np + 4 * q];

    // batch-invariant planet masses (planet 16*i + lm)
    float pmv[8];
    #pragma unroll
    for (int i = 0; i < 8; i++)
        pmv[i] = planet_m[16 * i + lm];

    const unsigned int bf0_const = q1 ? pack_pkrtz(1.f, 0.f) : 0u;
    const f32x4 zf = (f32x4){0.f, 0.f, 0.f, 0.f};

    int b = (blockIdx.x * WPB + wv) * ITERS;

    for (int it = 0; it < ITERS; ++it, ++b) {
        const float2 axy = *(const float2*)&ast_xy[2 * b];
        float2 pxy[8];
        #pragma unroll
        for (int i = 0; i < 8; i++)
            pxy[i] = *(const float2*)&planet_xy[((size_t)b * NP + 16 * i + lm) * 2];

        f32x4 sums[4];
        #pragma unroll
        for (int np = 0; np < 4; np++)
            sums[np] = zf;

        #pragma unroll
        for (int mi = 0; mi < 8; ++mi) {
            // feats B-frag for planets 16mi..16mi+15
            float dx = pxy[mi].x - axy.x, dy = pxy[mi].y - axy.y;
            float inv = __builtin_amdgcn_rsqf(fmaf(dx, dx, fmaf(dy, dy, 1e-6f)));
            FragK16 bf;
            bf.u[0] = q0 ? pack_pkrtz(dx, dy)        : bf0_const;
            bf.u[1] = q0 ? pack_pkrtz(inv, pmv[mi])  : 0u;

            // layer1: hT fragments straight into registers (K16 C layout)
            FragK16 hb[4];
            #pragma unroll
            for (int mt = 0; mt < 4; mt++) {
                f32x4 c = __builtin_amdgcn_mfma_f32_16x16x16f16(w1f[mt].v, bf.v, zf, 0, 0, 0);
                hb[mt].u[0] = relu2_pk(pack_pkrtz(c[0], c[1]));
                hb[mt].u[1] = relu2_pk(pack_pkrtz(c[2], c[3]));
            }

            // sigma-ordered K32 B-frags: pure register concatenation of hb pairs
            FragK32 hB[2];
            #pragma unroll
            for (int kk = 0; kk < 2; kk++) {
                hB[kk].u[0] = hb[2 * kk + 0].u[0];
                hB[kk].u[1] = hb[2 * kk + 0].u[1];
                hB[kk].u[2] = hb[2 * kk + 1].u[0];
                hB[kk].u[3] = hb[2 * kk + 1].u[1];
            }

            // layer2: msgT tile (rows n=16np+4q+r, col p=lm), full-rate K32
            #pragma unroll
            for (int np = 0; np < 4; np++) {
                f32x4 acc = __builtin_amdgcn_mfma_f32_16x16x32_f16(w2a[np][0].v, hB[0].v, b2f[np], 0, 0, 0);
                acc = __builtin_amdgcn_mfma_f32_16x16x32_f16(w2a[np][1].v, hB[1].v, acc, 0, 0, 0);
                sums[np] += __builtin_elementwise_max(acc, zf);   // relu + accumulate
            }
        }

        // ---- per-batch transpose-reduce over the 16 lm lanes via LDS ----
        #pragma unroll
        for (int np = 0; np < 4; np++)
            #pragma unroll
            for (int r = 0; r < 4; r++)
                rsum[wv][(16 * np + 4 * q + r) * RST + lm] = sums[np][r];

        // same-wave in-order DS: reads below observe the writes above
        float tot = 0.f;
        #pragma unroll
        for (int i = 0; i < 8; i++) {
            float2 v = *(const float2*)&rsum[wv][lane * RST + 2 * i];
            tot += v.x + v.y;
        }
        out[(size_t)b * NH + lane] = tot;
    }
}

extern "C" void kernel_launch(void* const* d_in, const int* in_sizes, int n_in,
                              void* d_out, int out_size, void* d_ws, size_t ws_size,
                              hipStream_t stream) {
    const float* planet_xy = (const float*)d_in[0];
    const float* planet_m  = (const float*)d_in[1];
    const float* ast_xy    = (const float*)d_in[2];
    const float* W1        = (const float*)d_in[3];
    const float* b1        = (const float*)d_in[4];
    const float* W2        = (const float*)d_in[5];
    const float* b2        = (const float*)d_in[6];
    float* outp            = (float*)d_out;

    const int B = in_sizes[2] / 2;   // ast_xy is [B][2]
    const int batches_per_block = WPB * ITERS;
    const int grid = (B + batches_per_block - 1) / batches_per_block;

    gnn_wave<<<grid, 256, 0, stream>>>(planet_xy, planet_m, ast_xy, W1, b1, W2, b2, outp);
}